// Round 12
// baseline (299.107 us; speedup 1.0000x reference)
//
#include <hip/hip_runtime.h>
#include <math.h>

#define NV 4096      // variable nodes
#define MC 2048      // check nodes
#define DV 3
#define DC 6
#define NE (NV * DV) // 12288 edges
#define NB 2048      // batch
#define NITER 5
#define TPB 1024     // 16 waves/block; 2 blocks/CU -> 32 waves/CU

typedef float f32x2 __attribute__((ext_vector_type(2)));

static __device__ __forceinline__ f32x2 vmax2(f32x2 a, f32x2 b) {
    f32x2 r; r.x = fmaxf(a.x, b.x); r.y = fmaxf(a.y, b.y); return r;
}

// Build per-check-node edge lists (slot order arbitrary due to atomics).
__global__ __launch_bounds__(256) void build_cn(const int* __restrict__ cn_idx,
                                                int* __restrict__ cn_edges,
                                                int* __restrict__ cn_cnt) {
    int e = blockIdx.x * 256 + threadIdx.x;
    if (e < NE) {
        int m = cn_idx[e];
        int slot = atomicAdd(&cn_cnt[m], 1);
        cn_edges[m * DC + slot] = e;
    }
}

// Sort each CN's 6 edges ascending -> deterministic, matches ref edge order.
__global__ __launch_bounds__(256) void sort_cn(int* __restrict__ cn_edges) {
    int m = blockIdx.x * 256 + threadIdx.x;
    if (m < MC) {
        int v[DC];
        for (int j = 0; j < DC; ++j) v[j] = cn_edges[m * DC + j];
        for (int i = 1; i < DC; ++i) {
            int key = v[i]; int j = i - 1;
            while (j >= 0 && v[j] > key) { v[j + 1] = v[j]; --j; }
            v[j + 1] = key;
        }
        for (int j = 0; j < DC; ++j) cn_edges[m * DC + j] = v[j];
    }
}

// R7 shell (one sample/block, 48 KB edge-major LDS, 2 blocks/CU) with the
// thread's TWO independent CN chains packed lane-wise into f32x2 so the
// product/num/den arithmetic lowers to gfx950 packed-FP32 (v_pk_*: 2x FLOPs
// per issue slot). Transcendentals stay scalar; sign bits stay int; each
// component's op sequence is bit-identical to R7 [absmax 1.0 proven].
//
// CN math (product domain): u = e^{-|mw|}; exclusion products of (1+-u) via
// prefix arrays + running suffix (3-pass keeps only u[] live, R9 lesson);
// val = ln((Pp+Pm)/max(Pp-Pm, 2^-23*Pp))  [== ref clip at float32(1-1e-7)];
// sign = bit-parity XOR (exact).
__global__ __launch_bounds__(TPB, 8) void bp_iter(const float* __restrict__ noise_r,
                                                  const float* __restrict__ ew,
                                                  const int* __restrict__ cn_edges,
                                                  float* __restrict__ out) {
    __shared__ float msg[NE];
    const int b = blockIdx.x;
    const int t = threadIdx.x;

    const float NO   = (float)0.3981071705534972;          // 1/(R*2*10^(EbNo/10))
    const float NSTD = sqrtf((float)(0.3981071705534972 * 0.5));

    // Edge lists of this thread's two CNs (cold data; spill tolerated per R7).
    int e0[DC], e1[DC];
#pragma unroll
    for (int j = 0; j < DC; ++j) {
        e0[j] = cn_edges[t * DC + j];
        e1[j] = cn_edges[(t + TPB) * DC + j];
    }

    float llr[NV / TPB];
    const float* nb = noise_r + (size_t)b * NV;
#pragma unroll
    for (int k = 0; k < NV / TPB; ++k) {
        int n = t + TPB * k;
        float y = 1.0f + NSTD * nb[n];
        float l = (4.0f * y) / NO;
        llr[k] = l;
        msg[3 * n + 0] = l * ew[3 * n + 0];
        msg[3 * n + 1] = l * ew[3 * n + 1];
        msg[3 * n + 2] = l * ew[3 * n + 2];
    }
    __syncthreads();

    for (int it = 0; it < NITER; ++it) {
        // ---- CN phase: both CNs in packed f32x2 lanes ----
        // pass 1: gather + exp (scalar trans), sign bits
        f32x2 u[DC];
        unsigned s0 = 0u, s1 = 0u;
#pragma unroll
        for (int j = 0; j < DC; ++j) {
            float mA = msg[e0[j]];
            float mB = msg[e1[j]];
            s0 |= ((__float_as_uint(mA) >> 31) & 1u) << j;
            s1 |= ((__float_as_uint(mB) >> 31) & 1u) << j;
            u[j].x = __expf(-fabsf(mA));
            u[j].y = __expf(-fabsf(mB));
        }
        const unsigned p0 = __popc(s0) & 1u;
        const unsigned p1 = __popc(s1) & 1u;

        // pass 2: forward prefix products of (1+u) and (1-u)   [packed]
        f32x2 pp[DC], pm[DC];
        f32x2 rp = {1.0f, 1.0f}, rm = {1.0f, 1.0f};
#pragma unroll
        for (int j = 0; j < DC; ++j) {
            pp[j] = rp;
            pm[j] = rm;
            rp *= (1.0f + u[j]);
            rm *= (1.0f - u[j]);
        }

        // pass 3: backward running suffix; combine, log, write  [packed]
        f32x2 sp = {1.0f, 1.0f}, sm = {1.0f, 1.0f};
#pragma unroll
        for (int j = DC - 1; j >= 0; --j) {
            f32x2 Pp  = pp[j] * sp;
            f32x2 Pm  = pm[j] * sm;
            f32x2 num = Pp + Pm;
            f32x2 den = vmax2(Pp - Pm, 0x1.0p-23f * Pp);   // == ref clip 1-2^-23
            float vA = __logf(__fdividef(num.x, den.x));   // >= 0
            float vB = __logf(__fdividef(num.y, den.y));
            msg[e0[j]] = __uint_as_float(__float_as_uint(vA) |
                                         (((p0 ^ (s0 >> j)) & 1u) << 31));
            msg[e1[j]] = __uint_as_float(__float_as_uint(vB) |
                                         (((p1 ^ (s1 >> j)) & 1u) << 31));
            sp *= (1.0f + u[j]);
            sm *= (1.0f - u[j]);
        }
        __syncthreads();

        // ---- VN phase: each thread owns 4 variable nodes (as R7) ----
        if (it < NITER - 1) {
#pragma unroll
            for (int k = 0; k < NV / TPB; ++k) {
                int n = t + TPB * k;
                float c0 = msg[3 * n + 0];
                float c1 = msg[3 * n + 1];
                float c2 = msg[3 * n + 2];
                float tot = llr[k] + (c0 + c1 + c2);
                msg[3 * n + 0] = (tot - c0) * ew[3 * n + 0];
                msg[3 * n + 1] = (tot - c1) * ew[3 * n + 1];
                msg[3 * n + 2] = (tot - c2) * ew[3 * n + 2];
            }
            __syncthreads();
        } else {
#pragma unroll
            for (int k = 0; k < NV / TPB; ++k) {
                int n = t + TPB * k;
                float c0 = msg[3 * n + 0];
                float c1 = msg[3 * n + 1];
                float c2 = msg[3 * n + 2];
                out[(size_t)b * NV + n] = llr[k] + (c0 + c1 + c2);
            }
        }
    }
}

extern "C" void kernel_launch(void* const* d_in, const int* in_sizes, int n_in,
                              void* d_out, int out_size, void* d_ws, size_t ws_size,
                              hipStream_t stream) {
    const float* noise_r = (const float*)d_in[0];
    // d_in[1] = noise_i (unused by reference)
    const float* ew      = (const float*)d_in[2];
    // d_in[3] = vn_idx: known structure e // 3 (edges contiguous per VN)
    const int*   cn_idx  = (const int*)d_in[4];
    float* out = (float*)d_out;

    int* cn_edges = (int*)d_ws;        // NE ints
    int* cn_cnt   = cn_edges + NE;     // MC ints

    hipMemsetAsync(cn_cnt, 0, MC * sizeof(int), stream);
    build_cn<<<(NE + 255) / 256, 256, 0, stream>>>(cn_idx, cn_edges, cn_cnt);
    sort_cn<<<(MC + 255) / 256, 256, 0, stream>>>(cn_edges);
    bp_iter<<<NB, TPB, 0, stream>>>(noise_r, ew, cn_edges, out);
}

// Round 13
// 166.083 us; speedup vs baseline: 1.8009x; 1.8009x over previous
//
#include <hip/hip_runtime.h>
#include <math.h>

#define NV 4096      // variable nodes
#define MC 2048      // check nodes
#define DV 3
#define DC 6
#define NE (NV * DV) // 12288 edges
#define NB 2048      // batch
#define NITER 5
#define TPB 512      // 8 waves/block; 3 blocks/CU (144KB LDS) -> 24 waves/CU
#define CPT (MC / TPB)   // 4 check nodes per thread
#define VPT (NV / TPB)   // 8 variable nodes per thread

// Build per-check-node edge lists (slot order arbitrary due to atomics).
__global__ __launch_bounds__(256) void build_cn(const int* __restrict__ cn_idx,
                                                int* __restrict__ cn_edges,
                                                int* __restrict__ cn_cnt) {
    int e = blockIdx.x * 256 + threadIdx.x;
    if (e < NE) {
        int m = cn_idx[e];
        int slot = atomicAdd(&cn_cnt[m], 1);
        cn_edges[m * DC + slot] = e;
    }
}

// Sort each CN's 6 edges ascending -> deterministic, matches ref edge order.
__global__ __launch_bounds__(256) void sort_cn(int* __restrict__ cn_edges) {
    int m = blockIdx.x * 256 + threadIdx.x;
    if (m < MC) {
        int v[DC];
        for (int j = 0; j < DC; ++j) v[j] = cn_edges[m * DC + j];
        for (int i = 1; i < DC; ++i) {
            int key = v[i]; int j = i - 1;
            while (j >= 0 && v[j] > key) { v[j + 1] = v[j]; --j; }
            v[j + 1] = key;
        }
        for (int j = 0; j < DC; ++j) cn_edges[m * DC + j] = v[j];
    }
}

// R7 structure at TPB=512: one sample/block, 48 KB edge-major LDS message
// array, two-phase barriers. (512,6) gives VGPR cap 84 (vs 64 at 1024,8) so
// the working set fits with NO spill, while 3 blocks/CU keep 24 waves (75%).
// Edge-index table packed as u16 pairs (6 cold regs). Math byte-identical to
// R7 [absmax 1.0 proven]: u = e^{-|mw|}; exclusion products of (1+-u) via
// prefix arrays + running suffix; val = ln((Pp+Pm)/max(Pp-Pm, 2^-23*Pp))
// [== ref clip at float32(1-1e-7)]; sign = bit-parity XOR (exact).
__global__ __launch_bounds__(TPB, 6) void bp_iter(const float* __restrict__ noise_r,
                                                  const float* __restrict__ ew,
                                                  const int* __restrict__ cn_edges,
                                                  float* __restrict__ out) {
    __shared__ float msg[NE];
    const int b = blockIdx.x;
    const int t = threadIdx.x;

    const float NO   = (float)0.3981071705534972;          // 1/(R*2*10^(EbNo/10))
    const float NSTD = sqrtf((float)(0.3981071705534972 * 0.5));

    // Edge lists of this thread's 4 CNs, packed 2 x u16 per reg (cold data).
    unsigned wpk[CPT][3];
#pragma unroll
    for (int c = 0; c < CPT; ++c) {
        const int* ep = cn_edges + (t + TPB * c) * DC;
#pragma unroll
        for (int i = 0; i < 3; ++i)
            wpk[c][i] = (unsigned)ep[2 * i] | ((unsigned)ep[2 * i + 1] << 16);
    }

    float llr[VPT];
    const float* nb = noise_r + (size_t)b * NV;
#pragma unroll
    for (int k = 0; k < VPT; ++k) {
        int n = t + TPB * k;
        float y = 1.0f + NSTD * nb[n];
        float l = (4.0f * y) / NO;
        llr[k] = l;
        msg[3 * n + 0] = l * ew[3 * n + 0];
        msg[3 * n + 1] = l * ew[3 * n + 1];
        msg[3 * n + 2] = l * ew[3 * n + 2];
    }
    __syncthreads();

    for (int it = 0; it < NITER; ++it) {
        // ---- CN phase: each thread owns 4 check nodes, processed serially ----
#pragma unroll
        for (int c = 0; c < CPT; ++c) {
            int idx[DC];
#pragma unroll
            for (int j = 0; j < DC; ++j)
                idx[j] = (int)((wpk[c][j >> 1] >> ((j & 1) * 16)) & 0xffffu);

            float u[DC];
            unsigned spack = 0u;
#pragma unroll
            for (int j = 0; j < DC; ++j) {
                float mw = msg[idx[j]];
                spack |= ((__float_as_uint(mw) >> 31) & 1u) << j;
                u[j] = __expf(-fabsf(mw));
            }
            const unsigned par = __popc(spack) & 1u;

            // forward prefix products of (1+u), (1-u)
            float pp[DC], pm[DC];
            float rp = 1.0f, rm = 1.0f;
#pragma unroll
            for (int j = 0; j < DC; ++j) {
                pp[j] = rp;
                pm[j] = rm;
                rp *= (1.0f + u[j]);
                rm *= (1.0f - u[j]);
            }

            // backward running suffix; combine, log, write
            float sp = 1.0f, sm = 1.0f;
#pragma unroll
            for (int j = DC - 1; j >= 0; --j) {
                float Pp  = pp[j] * sp;
                float Pm  = pm[j] * sm;
                float num = Pp + Pm;
                float den = fmaxf(Pp - Pm, 0x1.0p-23f * Pp);   // == ref clip 1-2^-23
                float val = __logf(__fdividef(num, den));      // >= 0
                msg[idx[j]] = __uint_as_float(__float_as_uint(val) |
                                              (((par ^ (spack >> j)) & 1u) << 31));
                sp *= (1.0f + u[j]);
                sm *= (1.0f - u[j]);
            }
        }
        __syncthreads();

        // ---- VN phase: each thread owns 8 variable nodes ----
        if (it < NITER - 1) {
#pragma unroll
            for (int k = 0; k < VPT; ++k) {
                int n = t + TPB * k;
                float c0 = msg[3 * n + 0];
                float c1 = msg[3 * n + 1];
                float c2 = msg[3 * n + 2];
                float tot = llr[k] + (c0 + c1 + c2);
                msg[3 * n + 0] = (tot - c0) * ew[3 * n + 0];
                msg[3 * n + 1] = (tot - c1) * ew[3 * n + 1];
                msg[3 * n + 2] = (tot - c2) * ew[3 * n + 2];
            }
            __syncthreads();
        } else {
#pragma unroll
            for (int k = 0; k < VPT; ++k) {
                int n = t + TPB * k;
                float c0 = msg[3 * n + 0];
                float c1 = msg[3 * n + 1];
                float c2 = msg[3 * n + 2];
                out[(size_t)b * NV + n] = llr[k] + (c0 + c1 + c2);
            }
        }
    }
}

extern "C" void kernel_launch(void* const* d_in, const int* in_sizes, int n_in,
                              void* d_out, int out_size, void* d_ws, size_t ws_size,
                              hipStream_t stream) {
    const float* noise_r = (const float*)d_in[0];
    // d_in[1] = noise_i (unused by reference)
    const float* ew      = (const float*)d_in[2];
    // d_in[3] = vn_idx: known structure e // 3 (edges contiguous per VN)
    const int*   cn_idx  = (const int*)d_in[4];
    float* out = (float*)d_out;

    int* cn_edges = (int*)d_ws;        // NE ints
    int* cn_cnt   = cn_edges + NE;     // MC ints

    hipMemsetAsync(cn_cnt, 0, MC * sizeof(int), stream);
    build_cn<<<(NE + 255) / 256, 256, 0, stream>>>(cn_idx, cn_edges, cn_cnt);
    sort_cn<<<(MC + 255) / 256, 256, 0, stream>>>(cn_edges);
    bp_iter<<<NB, TPB, 0, stream>>>(noise_r, ew, cn_edges, out);
}

// Round 14
// 148.629 us; speedup vs baseline: 2.0124x; 1.1174x over previous
//
#include <hip/hip_runtime.h>
#include <math.h>

#define NV 4096      // variable nodes
#define MC 2048      // check nodes
#define DV 3
#define DC 6
#define NE (NV * DV) // 12288 edges
#define NB 2048      // batch
#define NITER 5
#define TPB 1024     // 16 waves/block; 2 blocks/CU -> 32 waves/CU

// Build per-check-node edge lists (slot order arbitrary due to atomics).
__global__ __launch_bounds__(256) void build_cn(const int* __restrict__ cn_idx,
                                                int* __restrict__ cn_edges,
                                                int* __restrict__ cn_cnt) {
    int e = blockIdx.x * 256 + threadIdx.x;
    if (e < NE) {
        int m = cn_idx[e];
        int slot = atomicAdd(&cn_cnt[m], 1);
        cn_edges[m * DC + slot] = e;
    }
}

// Sort each CN's 6 edges ascending -> deterministic, matches ref edge order.
__global__ __launch_bounds__(256) void sort_cn(int* __restrict__ cn_edges) {
    int m = blockIdx.x * 256 + threadIdx.x;
    if (m < MC) {
        int v[DC];
        for (int j = 0; j < DC; ++j) v[j] = cn_edges[m * DC + j];
        for (int i = 1; i < DC; ++i) {
            int key = v[i]; int j = i - 1;
            while (j >= 0 && v[j] > key) { v[j + 1] = v[j]; --j; }
            v[j + 1] = key;
        }
        for (int j = 0; j < DC; ++j) cn_edges[m * DC + j] = v[j];
    }
}

// R7 shell: one sample/block, 48 KB edge-major LDS, two-phase barriers,
// (1024,8) -> 2 blocks/CU. CN math WITHOUT prefix/suffix arrays:
//   u = e^{-|mw|}; a = 1+u; b = max(1-u, 1e-12)   [floor == ref's |t|+1e-12
//                                                  semantics at t~0; avoids 0/0]
//   P = PROD a_i;  M = PROD b_i                    [only u[6],P,M live -> ~16
//                                                  peak regs, fits 64-cap]
//   excl ratio: (Pp_j+Pm_j)/(Pp_j-Pm_j) == (P*b_j + M*a_j)/(P*b_j - M*a_j)
//               (the a_j*b_j factor cancels exactly)
//   val = ln(num / max(den, 2^-23 * P*b_j))        [== ref clip at 1-2^-23]
//   sign = bit-parity XOR (exact == ref mod-2).
__global__ __launch_bounds__(TPB, 8) void bp_iter(const float* __restrict__ noise_r,
                                                  const float* __restrict__ ew,
                                                  const int* __restrict__ cn_edges,
                                                  float* __restrict__ out) {
    __shared__ float msg[NE];
    const int b = blockIdx.x;
    const int t = threadIdx.x;

    const float NO   = (float)0.3981071705534972;          // 1/(R*2*10^(EbNo/10))
    const float NSTD = sqrtf((float)(0.3981071705534972 * 0.5));

    // Edge lists of this thread's 2 CNs, packed 2 x u16 per reg (6 regs).
    unsigned wpk[MC / TPB][3];
#pragma unroll
    for (int c = 0; c < MC / TPB; ++c) {
        const int* ep = cn_edges + (t + TPB * c) * DC;
#pragma unroll
        for (int i = 0; i < 3; ++i)
            wpk[c][i] = (unsigned)ep[2 * i] | ((unsigned)ep[2 * i + 1] << 16);
    }

    float llr[NV / TPB];
    const float* nb = noise_r + (size_t)b * NV;
#pragma unroll
    for (int k = 0; k < NV / TPB; ++k) {
        int n = t + TPB * k;
        float y = 1.0f + NSTD * nb[n];
        float l = (4.0f * y) / NO;
        llr[k] = l;
        msg[3 * n + 0] = l * ew[3 * n + 0];
        msg[3 * n + 1] = l * ew[3 * n + 1];
        msg[3 * n + 2] = l * ew[3 * n + 2];
    }
    __syncthreads();

    for (int it = 0; it < NITER; ++it) {
        // ---- CN phase: each thread owns 2 check nodes ----
#pragma unroll
        for (int c = 0; c < MC / TPB; ++c) {
            int idx[DC];
#pragma unroll
            for (int j = 0; j < DC; ++j)
                idx[j] = (int)((wpk[c][j >> 1] >> ((j & 1) * 16)) & 0xffffu);

            float u[DC];
            unsigned spack = 0u;
#pragma unroll
            for (int j = 0; j < DC; ++j) {
                float mw = msg[idx[j]];
                spack |= ((__float_as_uint(mw) >> 31) & 1u) << j;
                u[j] = __expf(-fabsf(mw));
            }
            const unsigned par = __popc(spack) & 1u;

            float P = 1.0f, M = 1.0f;
#pragma unroll
            for (int j = 0; j < DC; ++j) {
                P *= (1.0f + u[j]);
                M *= fmaxf(1.0f - u[j], 1e-12f);
            }

#pragma unroll
            for (int j = 0; j < DC; ++j) {
                float aj  = 1.0f + u[j];
                float bj  = fmaxf(1.0f - u[j], 1e-12f);
                float Pb  = P * bj;
                float Ma  = M * aj;
                float num = Pb + Ma;
                float den = fmaxf(Pb - Ma, 0x1.0p-23f * Pb);   // == ref clip 1-2^-23
                float val = __logf(__fdividef(num, den));      // >= 0
                msg[idx[j]] = __uint_as_float(__float_as_uint(val) |
                                              (((par ^ (spack >> j)) & 1u) << 31));
            }
        }
        __syncthreads();

        // ---- VN phase: each thread owns 4 variable nodes ----
        if (it < NITER - 1) {
#pragma unroll
            for (int k = 0; k < NV / TPB; ++k) {
                int n = t + TPB * k;
                float c0 = msg[3 * n + 0];
                float c1 = msg[3 * n + 1];
                float c2 = msg[3 * n + 2];
                float tot = llr[k] + (c0 + c1 + c2);
                msg[3 * n + 0] = (tot - c0) * ew[3 * n + 0];
                msg[3 * n + 1] = (tot - c1) * ew[3 * n + 1];
                msg[3 * n + 2] = (tot - c2) * ew[3 * n + 2];
            }
            __syncthreads();
        } else {
#pragma unroll
            for (int k = 0; k < NV / TPB; ++k) {
                int n = t + TPB * k;
                float c0 = msg[3 * n + 0];
                float c1 = msg[3 * n + 1];
                float c2 = msg[3 * n + 2];
                out[(size_t)b * NV + n] = llr[k] + (c0 + c1 + c2);
            }
        }
    }
}

extern "C" void kernel_launch(void* const* d_in, const int* in_sizes, int n_in,
                              void* d_out, int out_size, void* d_ws, size_t ws_size,
                              hipStream_t stream) {
    const float* noise_r = (const float*)d_in[0];
    // d_in[1] = noise_i (unused by reference)
    const float* ew      = (const float*)d_in[2];
    // d_in[3] = vn_idx: known structure e // 3 (edges contiguous per VN)
    const int*   cn_idx  = (const int*)d_in[4];
    float* out = (float*)d_out;

    int* cn_edges = (int*)d_ws;        // NE ints
    int* cn_cnt   = cn_edges + NE;     // MC ints

    hipMemsetAsync(cn_cnt, 0, MC * sizeof(int), stream);
    build_cn<<<(NE + 255) / 256, 256, 0, stream>>>(cn_idx, cn_edges, cn_cnt);
    sort_cn<<<(MC + 255) / 256, 256, 0, stream>>>(cn_edges);
    bp_iter<<<NB, TPB, 0, stream>>>(noise_r, ew, cn_edges, out);
}

// Round 15
// 147.549 us; speedup vs baseline: 2.0272x; 1.0073x over previous
//
#include <hip/hip_runtime.h>
#include <math.h>

#define NV 4096      // variable nodes
#define MC 2048      // check nodes
#define DV 3
#define DC 6
#define NE (NV * DV) // 12288 edges
#define NB 2048      // batch
#define NITER 5
#define TPB 1024     // 16 waves/block; 2 blocks/CU -> 32 waves/CU

// Build per-check-node edge lists (slot order arbitrary due to atomics).
__global__ __launch_bounds__(256) void build_cn(const int* __restrict__ cn_idx,
                                                int* __restrict__ cn_edges,
                                                int* __restrict__ cn_cnt) {
    int e = blockIdx.x * 256 + threadIdx.x;
    if (e < NE) {
        int m = cn_idx[e];
        int slot = atomicAdd(&cn_cnt[m], 1);
        cn_edges[m * DC + slot] = e;
    }
}

// Sort each CN's 6 edges ascending -> deterministic, matches ref edge order.
__global__ __launch_bounds__(256) void sort_cn(int* __restrict__ cn_edges) {
    int m = blockIdx.x * 256 + threadIdx.x;
    if (m < MC) {
        int v[DC];
        for (int j = 0; j < DC; ++j) v[j] = cn_edges[m * DC + j];
        for (int i = 1; i < DC; ++i) {
            int key = v[i]; int j = i - 1;
            while (j >= 0 && v[j] > key) { v[j + 1] = v[j]; --j; }
            v[j + 1] = key;
        }
        for (int j = 0; j < DC; ++j) cn_edges[m * DC + j] = v[j];
    }
}

// R13 structure (best, clean): one sample/block, 48 KB edge-major LDS,
// two-phase barriers, (1024,8) -> 2 blocks/CU. Micro-cuts this round:
//  - edge word-indices unpacked ONCE before the iter loop (12 cold regs)
//  - a[]/b[] cached from pass 1 (phase-local; no recompute in output pass)
// CN math (byte-identical to R13, absmax 1.0 proven):
//   u = e^{-|mw|}; a = 1+u; b = max(1-u, 1e-12)
//   P = PROD a_i; M = PROD b_i
//   val_j = ln((P*b_j + M*a_j) / max(P*b_j - M*a_j, 2^-23 * P*b_j))
//           [den floor == ref clip at float32(1-1e-7) = 1-2^-23]
//   sign = bit-parity XOR (exact == ref mod-2).
__global__ __launch_bounds__(TPB, 8) void bp_iter(const float* __restrict__ noise_r,
                                                  const float* __restrict__ ew,
                                                  const int* __restrict__ cn_edges,
                                                  float* __restrict__ out) {
    __shared__ float msg[NE];
    const int b = blockIdx.x;
    const int t = threadIdx.x;

    const float NO   = (float)0.3981071705534972;          // 1/(R*2*10^(EbNo/10))
    const float NSTD = sqrtf((float)(0.3981071705534972 * 0.5));

    // Edge lists of this thread's 2 CNs, unpacked word indices (loop-invariant).
    int idx[MC / TPB][DC];
#pragma unroll
    for (int c = 0; c < MC / TPB; ++c)
#pragma unroll
        for (int j = 0; j < DC; ++j)
            idx[c][j] = cn_edges[(t + TPB * c) * DC + j];

    float llr[NV / TPB];
    const float* nb = noise_r + (size_t)b * NV;
#pragma unroll
    for (int k = 0; k < NV / TPB; ++k) {
        int n = t + TPB * k;
        float y = 1.0f + NSTD * nb[n];
        float l = (4.0f * y) / NO;
        llr[k] = l;
        msg[3 * n + 0] = l * ew[3 * n + 0];
        msg[3 * n + 1] = l * ew[3 * n + 1];
        msg[3 * n + 2] = l * ew[3 * n + 2];
    }
    __syncthreads();

    for (int it = 0; it < NITER; ++it) {
        // ---- CN phase: each thread owns 2 check nodes ----
#pragma unroll
        for (int c = 0; c < MC / TPB; ++c) {
            float a[DC], bb[DC];
            unsigned spack = 0u;
#pragma unroll
            for (int j = 0; j < DC; ++j) {
                float mw = msg[idx[c][j]];
                spack |= ((__float_as_uint(mw) >> 31) & 1u) << j;
                float u = __expf(-fabsf(mw));
                a[j]  = 1.0f + u;
                bb[j] = fmaxf(1.0f - u, 1e-12f);
            }
            const unsigned par = __popc(spack) & 1u;

            float P = 1.0f, M = 1.0f;
#pragma unroll
            for (int j = 0; j < DC; ++j) {
                P *= a[j];
                M *= bb[j];
            }

#pragma unroll
            for (int j = 0; j < DC; ++j) {
                float Pb  = P * bb[j];
                float Ma  = M * a[j];
                float num = Pb + Ma;
                float den = fmaxf(Pb - Ma, 0x1.0p-23f * Pb);   // == ref clip 1-2^-23
                float val = __logf(__fdividef(num, den));      // >= 0
                msg[idx[c][j]] = __uint_as_float(__float_as_uint(val) |
                                                 (((par ^ (spack >> j)) & 1u) << 31));
            }
        }
        __syncthreads();

        // ---- VN phase: each thread owns 4 variable nodes ----
        if (it < NITER - 1) {
#pragma unroll
            for (int k = 0; k < NV / TPB; ++k) {
                int n = t + TPB * k;
                float c0 = msg[3 * n + 0];
                float c1 = msg[3 * n + 1];
                float c2 = msg[3 * n + 2];
                float tot = llr[k] + (c0 + c1 + c2);
                msg[3 * n + 0] = (tot - c0) * ew[3 * n + 0];
                msg[3 * n + 1] = (tot - c1) * ew[3 * n + 1];
                msg[3 * n + 2] = (tot - c2) * ew[3 * n + 2];
            }
            __syncthreads();
        } else {
#pragma unroll
            for (int k = 0; k < NV / TPB; ++k) {
                int n = t + TPB * k;
                float c0 = msg[3 * n + 0];
                float c1 = msg[3 * n + 1];
                float c2 = msg[3 * n + 2];
                out[(size_t)b * NV + n] = llr[k] + (c0 + c1 + c2);
            }
        }
    }
}

extern "C" void kernel_launch(void* const* d_in, const int* in_sizes, int n_in,
                              void* d_out, int out_size, void* d_ws, size_t ws_size,
                              hipStream_t stream) {
    const float* noise_r = (const float*)d_in[0];
    // d_in[1] = noise_i (unused by reference)
    const float* ew      = (const float*)d_in[2];
    // d_in[3] = vn_idx: known structure e // 3 (edges contiguous per VN)
    const int*   cn_idx  = (const int*)d_in[4];
    float* out = (float*)d_out;

    int* cn_edges = (int*)d_ws;        // NE ints
    int* cn_cnt   = cn_edges + NE;     // MC ints

    hipMemsetAsync(cn_cnt, 0, MC * sizeof(int), stream);
    build_cn<<<(NE + 255) / 256, 256, 0, stream>>>(cn_idx, cn_edges, cn_cnt);
    sort_cn<<<(MC + 255) / 256, 256, 0, stream>>>(cn_edges);
    bp_iter<<<NB, TPB, 0, stream>>>(noise_r, ew, cn_edges, out);
}

// Round 16
// 122.053 us; speedup vs baseline: 2.4506x; 1.2089x over previous
//
#include <hip/hip_runtime.h>
#include <math.h>

#define NV 4096      // variable nodes
#define MC 2048      // check nodes
#define DV 3
#define DC 6
#define NE (NV * DV) // 12288 edges
#define NB 2048      // batch
#define NITER 5
#define TPB 1024     // 16 waves/block; 2 blocks/CU -> 32 waves/CU (HW wave cap)

// Build per-check-node edge lists (slot order arbitrary due to atomics).
__global__ __launch_bounds__(256) void build_cn(const int* __restrict__ cn_idx,
                                                int* __restrict__ cn_edges,
                                                int* __restrict__ cn_cnt) {
    int e = blockIdx.x * 256 + threadIdx.x;
    if (e < NE) {
        int m = cn_idx[e];
        int slot = atomicAdd(&cn_cnt[m], 1);
        cn_edges[m * DC + slot] = e;
    }
}

// Sort each CN's 6 edges ascending -> deterministic, matches ref edge order.
__global__ __launch_bounds__(256) void sort_cn(int* __restrict__ cn_edges) {
    int m = blockIdx.x * 256 + threadIdx.x;
    if (m < MC) {
        int v[DC];
        for (int j = 0; j < DC; ++j) v[j] = cn_edges[m * DC + j];
        for (int i = 1; i < DC; ++i) {
            int key = v[i]; int j = i - 1;
            while (j >= 0 && v[j] > key) { v[j + 1] = v[j]; --j; }
            v[j + 1] = key;
        }
        for (int j = 0; j < DC; ++j) cn_edges[m * DC + j] = v[j];
    }
}

// bare v_exp_f32 with -|x| folded as input modifier: u = 2^(-|x|)
static __device__ __forceinline__ float exp2_negabs(float x) {
    float r;
    asm volatile("v_exp_f32 %0, -abs(%1)" : "=v"(r) : "v"(x));
    return r;
}
// bare v_log_f32: log2(x)
static __device__ __forceinline__ float log2_raw(float x) {
    float r;
    asm volatile("v_log_f32 %0, %1" : "=v"(r) : "v"(x));
    return r;
}

// R13/R14 structure (one sample/block, 48 KB edge-major LDS, two-phase
// barriers, (1024,8) -> 2 blocks/CU = 32 waves = HW cap), with two
// SEMANTIC instruction cuts the compiler cannot perform:
//  (1) log2-domain: all LLRs/messages carry a log2(e) scale. Then
//      u = 2^{-|mw2|} == e^{-|mw|} is a bare v_exp_f32 (no pre-mul) and
//      val2 = log2(num/den) == ln(num/den)*log2e is a bare v_log_f32
//      (no post-mul). VN adds/weight-muls are scale-isomorphic; final
//      output multiplies by ln2 once per VN.
//  (2) sign via float product: s_j = copysign(1,mw) (v_bfi), running
//      product sprod; exclusion sign = sprod*s_j exactly (s^2=1);
//      applied as val*(sprod*s_j). Bit-identical to the parity path.
// CN math otherwise byte-equivalent to R13 [absmax 1.0 proven]:
//   a = 1+u; b = max(1-u,1e-12); P = PROD a; M = PROD b;
//   den floor 2^-23*P*b_j == ref clip at float32(1-1e-7) = 1-2^-23.
__global__ __launch_bounds__(TPB, 8) void bp_iter(const float* __restrict__ noise_r,
                                                  const float* __restrict__ ew,
                                                  const int* __restrict__ cn_edges,
                                                  float* __restrict__ out) {
    __shared__ float msg[NE];
    const int b = blockIdx.x;
    const int t = threadIdx.x;

    const float NO    = (float)0.3981071705534972;         // 1/(R*2*10^(EbNo/10))
    const float NSTD  = sqrtf((float)(0.3981071705534972 * 0.5));
    const float LOG2E = 1.4426950408889634f;
    const float LN2   = 0.6931471805599453f;

    // Edge lists of this thread's 2 CNs (loop-invariant).
    int idx[MC / TPB][DC];
#pragma unroll
    for (int c = 0; c < MC / TPB; ++c)
#pragma unroll
        for (int j = 0; j < DC; ++j)
            idx[c][j] = cn_edges[(t + TPB * c) * DC + j];

    float llr2[NV / TPB];   // log2-scaled channel LLRs
    const float* nb = noise_r + (size_t)b * NV;
#pragma unroll
    for (int k = 0; k < NV / TPB; ++k) {
        int n = t + TPB * k;
        float y  = 1.0f + NSTD * nb[n];
        float l  = (4.0f * y) / NO;
        float l2 = l * LOG2E;
        llr2[k] = l2;
        msg[3 * n + 0] = l2 * ew[3 * n + 0];
        msg[3 * n + 1] = l2 * ew[3 * n + 1];
        msg[3 * n + 2] = l2 * ew[3 * n + 2];
    }
    __syncthreads();

    for (int it = 0; it < NITER; ++it) {
        // ---- CN phase: each thread owns 2 check nodes ----
#pragma unroll
        for (int c = 0; c < MC / TPB; ++c) {
            float a[DC], bb[DC], s[DC];
            float sprod = 1.0f;
#pragma unroll
            for (int j = 0; j < DC; ++j) {
                float mw = msg[idx[c][j]];
                s[j] = copysignf(1.0f, mw);
                sprod *= s[j];
                float u = exp2_negabs(mw);          // 2^{-|mw2|} = e^{-|mw|}
                a[j]  = 1.0f + u;
                bb[j] = fmaxf(1.0f - u, 1e-12f);
            }

            float P = 1.0f, M = 1.0f;
#pragma unroll
            for (int j = 0; j < DC; ++j) {
                P *= a[j];
                M *= bb[j];
            }

#pragma unroll
            for (int j = 0; j < DC; ++j) {
                float Pb  = P * bb[j];
                float Ma  = M * a[j];
                float num = Pb + Ma;
                float den = fmaxf(Pb - Ma, 0x1.0p-23f * Pb);   // == ref clip 1-2^-23
                float val = log2_raw(__fdividef(num, den));    // >= 0, log2 domain
                msg[idx[c][j]] = val * (sprod * s[j]);         // exact +-1 sign
            }
        }
        __syncthreads();

        // ---- VN phase: each thread owns 4 variable nodes ----
        if (it < NITER - 1) {
#pragma unroll
            for (int k = 0; k < NV / TPB; ++k) {
                int n = t + TPB * k;
                float c0 = msg[3 * n + 0];
                float c1 = msg[3 * n + 1];
                float c2 = msg[3 * n + 2];
                float tot = llr2[k] + (c0 + c1 + c2);
                msg[3 * n + 0] = (tot - c0) * ew[3 * n + 0];
                msg[3 * n + 1] = (tot - c1) * ew[3 * n + 1];
                msg[3 * n + 2] = (tot - c2) * ew[3 * n + 2];
            }
            __syncthreads();
        } else {
#pragma unroll
            for (int k = 0; k < NV / TPB; ++k) {
                int n = t + TPB * k;
                float c0 = msg[3 * n + 0];
                float c1 = msg[3 * n + 1];
                float c2 = msg[3 * n + 2];
                out[(size_t)b * NV + n] = (llr2[k] + (c0 + c1 + c2)) * LN2;
            }
        }
    }
}

extern "C" void kernel_launch(void* const* d_in, const int* in_sizes, int n_in,
                              void* d_out, int out_size, void* d_ws, size_t ws_size,
                              hipStream_t stream) {
    const float* noise_r = (const float*)d_in[0];
    // d_in[1] = noise_i (unused by reference)
    const float* ew      = (const float*)d_in[2];
    // d_in[3] = vn_idx: known structure e // 3 (edges contiguous per VN)
    const int*   cn_idx  = (const int*)d_in[4];
    float* out = (float*)d_out;

    int* cn_edges = (int*)d_ws;        // NE ints
    int* cn_cnt   = cn_edges + NE;     // MC ints

    hipMemsetAsync(cn_cnt, 0, MC * sizeof(int), stream);
    build_cn<<<(NE + 255) / 256, 256, 0, stream>>>(cn_idx, cn_edges, cn_cnt);
    sort_cn<<<(MC + 255) / 256, 256, 0, stream>>>(cn_edges);
    bp_iter<<<NB, TPB, 0, stream>>>(noise_r, ew, cn_edges, out);
}